// Round 11
// baseline (515.187 us; speedup 1.0000x reference)
//
#include <hip/hip_runtime.h>
#include <hip/hip_bf16.h>
#include <math.h>

#define N_NODES 80000
#define N_EDGES 1280000
#define CHUNK 128
#define N_CHUNKS (N_EDGES / CHUNK)  // 10000
#define NBKT 8
#define BKT_DIV 10000               // bucket = dst / 10000  -> 0..7
#define BKT_CAP 165000              // mean 160000, sigma ~374; huge margin
#define EPB 1280                    // edges per k_part block (grid 1000)

typedef __hip_bfloat16 bf16;

__device__ __forceinline__ float leaky(float x) { return x >= 0.f ? x : 0.01f * x; }

// ---------------- setup kernels ----------------

__global__ void k_zero(int* deg, float* bnsums, int* tails) {
    int i = blockIdx.x * blockDim.x + threadIdx.x;
    if (i < N_NODES) deg[i] = 0;
    if (i < 384) bnsums[i] = 0.f;
    if (i < NBKT) tails[i] = 0;
}

// pass 1: bin raw (src,dst) pairs by dst-range; block bulk-reserves regions.
__global__ void __launch_bounds__(256)
k_part(const int* __restrict__ ei, int2* __restrict__ pairs,
       int* __restrict__ tails) {
    __shared__ int cnt[NBKT], off[NBKT];
    int t = threadIdx.x;
    if (t < NBKT) cnt[t] = 0;
    __syncthreads();
    int base = blockIdx.x * EPB;
    int2 loc[5];
#pragma unroll
    for (int u = 0; u < 5; ++u) {
        int e = base + u * 256 + t;
        int s = ei[e], d = ei[N_EDGES + e];
        loc[u] = make_int2(s, d);
        atomicAdd(&cnt[d / BKT_DIV], 1);
    }
    __syncthreads();
    if (t < NBKT) off[t] = atomicAdd(&tails[t], cnt[t]);
    __syncthreads();
#pragma unroll
    for (int u = 0; u < 5; ++u) {
        int b = loc[u].y / BKT_DIV;
        int pos = atomicAdd(&off[b], 1);
        pairs[(size_t)b * BKT_CAP + pos] = loc[u];
    }
}

// deg counting, bucket-pinned (atomics confined to a 40 KB dst slice).
__global__ void __launch_bounds__(256)
k_deg_bkt(const int2* __restrict__ pairs, const int* __restrict__ tails,
          int* __restrict__ deg) {
    int bucket = blockIdx.x & 7;
    int jb = blockIdx.x >> 3;
    int nb = gridDim.x >> 3;
    int cnt = tails[bucket];
    const int2* lst = pairs + (size_t)bucket * BKT_CAP;
    for (int i = jb * 256 + threadIdx.x; i < cnt; i += nb * 256)
        atomicAdd(&deg[lst[i].y], 1);
}

__global__ void k_scanA(const int* __restrict__ deg, int* __restrict__ partial,
                        float* __restrict__ dinv) {
    __shared__ int s[256];
    int t = threadIdx.x;
    int i = blockIdx.x * 256 + t;
    int v = (i < N_NODES) ? deg[i] : 0;
    if (i < N_NODES) dinv[i] = rsqrtf((float)v + 2.0f);  // + self-loop weight 2
    s[t] = v;
    __syncthreads();
    for (int off = 128; off > 0; off >>= 1) {
        if (t < off) s[t] += s[t + off];
        __syncthreads();
    }
    if (t == 0) partial[blockIdx.x] = s[0];
}

__global__ void k_scanB(int* partial, int nb) {
    __shared__ int s[512];
    int t = threadIdx.x;
    int v = (t < nb) ? partial[t] : 0;
    s[t] = v;
    __syncthreads();
    for (int off = 1; off < 512; off <<= 1) {
        int x = (t >= off) ? s[t - off] : 0;
        __syncthreads();
        s[t] += x;
        __syncthreads();
    }
    if (t < nb) partial[t] = s[t] - v;  // exclusive
}

__global__ void k_scanC(const int* __restrict__ deg, const int* __restrict__ partial,
                        int* __restrict__ cursor) {
    __shared__ int s[256];
    int t = threadIdx.x;
    int i = blockIdx.x * 256 + t;
    int v = (i < N_NODES) ? deg[i] : 0;
    s[t] = v;
    __syncthreads();
    for (int off = 1; off < 256; off <<= 1) {
        int x = (t >= off) ? s[t - off] : 0;
        __syncthreads();
        s[t] += x;
        __syncthreads();
    }
    if (i < N_NODES) cursor[i] = partial[blockIdx.x] + s[t] - v;
}

// pass 2: per-bucket CSR scatter of 4 B src-only records (dst recoverable
// from position via cursor). Halves the scattered-write payload vs int2.
__global__ void __launch_bounds__(256)
k_scatter2(const int2* __restrict__ pairs, const int* __restrict__ tails,
           int* __restrict__ cursor, int* __restrict__ ed) {
    int bucket = blockIdx.x & 7;
    int jb = blockIdx.x >> 3;
    int nb = gridDim.x >> 3;
    int cnt = tails[bucket];
    const int2* lst = pairs + (size_t)bucket * BKT_CAP;
    for (int i = jb * 256 + threadIdx.x; i < cnt; i += nb * 256) {
        int2 pr = lst[i];
        int p = atomicAdd(&cursor[pr.y], 1);
        ed[p] = pr.x;
    }
}

// chunk c -> first node owning edge c*CHUNK (binary search over rowend).
// chunk_node[N_CHUNKS] = -1 sentinel (never matches a node).
__global__ void k_chunknode(const int* __restrict__ cursor, int* __restrict__ chunk_node) {
    int c = blockIdx.x * blockDim.x + threadIdx.x;
    if (c > N_CHUNKS) return;
    if (c == N_CHUNKS) { chunk_node[c] = -1; return; }
    int e = c * CHUNK;
    int lo = 0, hi = N_NODES - 1;
    while (lo < hi) {
        int mid = (lo + hi) >> 1;
        if (cursor[mid] > e) hi = mid; else lo = mid + 1;
    }
    chunk_node[c] = lo;
}

// h0 = x @ W0; hs = bf16(dinv*h0)  (pre-scaled gather rows)
__global__ void k_h0s(const float* __restrict__ x, const float* __restrict__ W0,
                      const float* __restrict__ dinv, bf16* __restrict__ hs) {
    int tid = blockIdx.x * blockDim.x + threadIdx.x;
    if (tid < N_NODES * 64) {
        int v = tid >> 6, c = tid & 63;
        float x0 = x[v * 3], x1 = x[v * 3 + 1], x2 = x[v * 3 + 2];
        float h = x0 * W0[c] + x1 * W0[64 + c] + x2 * W0[128 + c];
        hs[tid] = __float2bfloat16(dinv[v] * h);
    }
}

// ---------------- per-stage kernels ----------------

// segmented aggregation over src-only CSR. Boundaries come from a 64-entry
// cursor window bulk-loaded into registers (one coalesced load per chunk;
// resolved via shfl — no memory latency on the accumulate chain).
// Flush = plain store unless the segment straddles a chunk boundary
// (lead / next-chunk-shares-node), then atomicAdd. yagg must be zeroed.
__global__ void __launch_bounds__(256)
k_agg_seg(const bf16* __restrict__ hs, const int* __restrict__ ed,
          const int* __restrict__ cursor, const int* __restrict__ chunk_node,
          float* __restrict__ yagg) {
    int lane = threadIdx.x & 63;
    int wid = (blockIdx.x * blockDim.x + threadIdx.x) >> 6;
    if (wid >= N_CHUNKS) return;
    int e0 = wid * CHUNK;
    int nwin = chunk_node[wid];
    int nextFirst = chunk_node[wid + 1];
    // cursor window: rowend for nodes nwin..nwin+63 in registers
    int wn = nwin + lane;
    int cw = cursor[wn < N_NODES ? wn : N_NODES - 1];
    int cur = nwin;
    int nextEnd = __shfl(cw, 0);
    bool lead = ((nwin > 0 ? cursor[nwin - 1] : 0) < e0);
    float acc = 0.f;
    int flushedUpTo = e0;
    int s[8];
#pragma unroll
    for (int u = 0; u < 8; ++u) s[u] = ed[e0 + u];
    int e = e0;
    for (int b = 0; b < CHUNK / 8; ++b) {
        float pv[8];
#pragma unroll
        for (int u = 0; u < 8; ++u)
            pv[u] = __bfloat162float(hs[(size_t)s[u] * 64 + lane]);
        int sn[8];
        if (b < CHUNK / 8 - 1) {
#pragma unroll
            for (int u = 0; u < 8; ++u) sn[u] = ed[e + 8 + u];
        }
#pragma unroll
        for (int u = 0; u < 8; ++u) {
            acc += pv[u];
            if (e + u + 1 == nextEnd) {
                if (lead) atomicAdd(&yagg[(size_t)cur * 64 + lane], acc);
                else yagg[(size_t)cur * 64 + lane] = acc;
                lead = false;
                acc = 0.f;
                flushedUpTo = e + u + 1;
                // advance past empty rows (rowend unchanged)
                int m = cur + 1;
                int re;
                for (;;) {
                    if (m >= N_NODES) { re = 0x7fffffff; break; }
                    re = (m - nwin < 64) ? __shfl(cw, m - nwin) : cursor[m];
                    if (re != nextEnd) break;
                    m++;
                }
                cur = m;
                nextEnd = re;
            }
        }
        e += 8;
        if (b < CHUNK / 8 - 1) {
#pragma unroll
            for (int u = 0; u < 8; ++u) s[u] = sn[u];
        }
    }
    if (flushedUpTo < e0 + CHUNK) {
        // trailing segment: atomic only if it extends beyond this chunk
        bool shared = lead || (nextFirst == cur);
        if (shared) atomicAdd(&yagg[(size_t)cur * 64 + lane], acc);
        else yagg[(size_t)cur * 64 + lane] = acc;
    }
}

// per-channel sum/sumsq of y_final = dinv[v]*(yagg + 2*hs_self) + bias[c]
__global__ void __launch_bounds__(256)
k_bnstats(const float* __restrict__ yagg, const bf16* __restrict__ hs,
          const float* __restrict__ dinv, const float* __restrict__ bias,
          float* __restrict__ bnsum) {
    int tid = blockIdx.x * blockDim.x + threadIdx.x;
    int stride = gridDim.x * blockDim.x;  // multiple of 64 -> lane == channel
    float bc = bias[tid & 63];
    float bs = 0.f, bss = 0.f;
    for (size_t i = tid; i < (size_t)N_NODES * 64; i += stride) {
        float comb = yagg[i] + 2.f * __bfloat162float(hs[i]);
        float yf = dinv[i >> 6] * comb + bc;
        bs += yf;
        bss += yf * yf;
    }
    __shared__ float s1[256], s2[256];
    s1[threadIdx.x] = bs;
    s2[threadIdx.x] = bss;
    __syncthreads();
    if (threadIdx.x < 64) {
        float t1 = s1[threadIdx.x] + s1[threadIdx.x + 64] + s1[threadIdx.x + 128] + s1[threadIdx.x + 192];
        float t2 = s2[threadIdx.x] + s2[threadIdx.x + 64] + s2[threadIdx.x + 128] + s2[threadIdx.x + 192];
        atomicAdd(&bnsum[threadIdx.x], t1);
        atomicAdd(&bnsum[64 + threadIdx.x], t2);
    }
}

// BN + maxpool + leaky + (a@lw.T+lb) + leaky + second matmul, register-tiled.
// Phase 1 input: y_final = dinv*(yagg + 2*hs_self) + bias (bias folded into BN shift).
// MODE 0: phase3 = o @ Wn (64x64) -> hs_next = bf16(dinv*hn).
// MODE 1: phase3 = o @ Wn (64x3)  -> hs3 = float4(dinv*h3).
template <int P, int MODE>
__global__ void __launch_bounds__(128)
k_post64(const float* __restrict__ yagg, const bf16* __restrict__ hs,
         const float* __restrict__ dinv, const float* __restrict__ bias,
         const float* __restrict__ bnsum,
         const float* __restrict__ g, const float* __restrict__ bb,
         const float* __restrict__ lw, const float* __restrict__ lb,
         const float* __restrict__ Wn, bf16* __restrict__ hsout,
         float4* __restrict__ hs3) {
    __shared__ float s_aT[2][64 * 36];  // per-wave activation tile (transposed), reused as oT
    __shared__ float s_lwT[64 * 64];    // lw transposed: [k][c]
    __shared__ float s_Wn[MODE == 0 ? 64 * 64 : 64 * 3];
    int t = threadIdx.x;
    int w = t >> 6, lane = t & 63;
    for (int k0 = t; k0 < 4096; k0 += 128) {
        int kk = k0 >> 6, cc = k0 & 63;
        s_lwT[kk * 64 + cc] = lw[cc * 64 + kk];
        if (MODE == 0) s_Wn[k0] = Wn[k0];
    }
    if (MODE == 1) {
        for (int i = t; i < 64 * 3; i += 128) s_Wn[i] = Wn[i];
    }
    float inv_n = 1.0f / (float)N_NODES;
    float mean = bnsum[lane] * inv_n;
    float var = fmaxf(bnsum[64 + lane] * inv_n - mean * mean, 0.f);
    float sc = g[lane] * rsqrtf(var + 1e-5f);
    float sh = bb[lane] - mean * sc;
    float shb = fmaf(sc, bias[lane], sh);  // folds GCN bias into BN shift
    int c0 = (lane >> 3) * 8, n0 = (lane & 7) * 4;
    float lbv[8];
#pragma unroll
    for (int i = 0; i < 8; ++i) lbv[i] = lb[c0 + i];
    float* aT = s_aT[w];

    for (int tile = blockIdx.x; tile < N_NODES / 64; tile += gridDim.x) {
        int nbase = tile * 64 + w * 32;
        __syncthreads();  // also covers initial weight-fill -> first use
#pragma unroll 4
        for (int i = 0; i < 32; ++i) {
            size_t idx = (size_t)(nbase + i) * 64 + lane;
            float comb = yagg[idx] + 2.f * __bfloat162float(hs[idx]);
            float z = fmaf(sc * dinv[nbase + i], comb, shb);
            float m = z;
#pragma unroll
            for (int d = 1; d <= P; ++d) {
                float up = __shfl(z, lane + d);
                float dn = __shfl(z, lane - d);
                m = fmaxf(m, (lane + d < 64) ? up : -INFINITY);
                m = fmaxf(m, (lane - d >= 0) ? dn : -INFINITY);
            }
            aT[lane * 36 + i] = leaky(m);
        }
        __syncthreads();
        // phase 2: o = leaky(a @ lw.T + lb)
        float acc[4][8];
#pragma unroll
        for (int nn = 0; nn < 4; ++nn)
#pragma unroll
            for (int i = 0; i < 8; ++i) acc[nn][i] = lbv[i];
#pragma unroll 8
        for (int k = 0; k < 64; ++k) {
            float4 av = *(const float4*)&aT[k * 36 + n0];
            float4 w0 = *(const float4*)&s_lwT[k * 64 + c0];
            float4 w1 = *(const float4*)&s_lwT[k * 64 + c0 + 4];
            float a4[4] = {av.x, av.y, av.z, av.w};
            float wv[8] = {w0.x, w0.y, w0.z, w0.w, w1.x, w1.y, w1.z, w1.w};
#pragma unroll
            for (int nn = 0; nn < 4; ++nn)
#pragma unroll
                for (int i = 0; i < 8; ++i) acc[nn][i] = fmaf(a4[nn], wv[i], acc[nn][i]);
        }
#pragma unroll
        for (int nn = 0; nn < 4; ++nn)
#pragma unroll
            for (int i = 0; i < 8; ++i) acc[nn][i] = leaky(acc[nn][i]);

        // write oT (aliases aT; same-wave LDS program order is safe)
#pragma unroll
        for (int i = 0; i < 8; ++i) {
            float4 ov = make_float4(acc[0][i], acc[1][i], acc[2][i], acc[3][i]);
            *(float4*)&aT[(c0 + i) * 36 + n0] = ov;
        }
        if (MODE == 0) {
            float acc2[4][8];
#pragma unroll
            for (int nn = 0; nn < 4; ++nn)
#pragma unroll
                for (int i = 0; i < 8; ++i) acc2[nn][i] = 0.f;
#pragma unroll 8
            for (int k = 0; k < 64; ++k) {
                float4 av = *(const float4*)&aT[k * 36 + n0];
                float4 w0 = *(const float4*)&s_Wn[k * 64 + c0];
                float4 w1 = *(const float4*)&s_Wn[k * 64 + c0 + 4];
                float a4[4] = {av.x, av.y, av.z, av.w};
                float wv[8] = {w0.x, w0.y, w0.z, w0.w, w1.x, w1.y, w1.z, w1.w};
#pragma unroll
                for (int nn = 0; nn < 4; ++nn)
#pragma unroll
                    for (int i = 0; i < 8; ++i) acc2[nn][i] = fmaf(a4[nn], wv[i], acc2[nn][i]);
            }
#pragma unroll
            for (int nn = 0; nn < 4; ++nn) {
                int node = nbase + n0 + nn;
                float dv = dinv[node];
                bf16 pk[8];
#pragma unroll
                for (int i = 0; i < 8; ++i) pk[i] = __float2bfloat16(dv * acc2[nn][i]);
                *(uint4*)&hsout[(size_t)node * 64 + c0] = *(uint4*)pk;
            }
        } else {
            // proj fused: h3 = o @ w2 (64x3); 8 lanes duplicate, c0==0 writes
            float acc3[4][3];
#pragma unroll
            for (int nn = 0; nn < 4; ++nn)
#pragma unroll
                for (int j = 0; j < 3; ++j) acc3[nn][j] = 0.f;
#pragma unroll 8
            for (int k = 0; k < 64; ++k) {
                float4 av = *(const float4*)&aT[k * 36 + n0];
                float a4[4] = {av.x, av.y, av.z, av.w};
                float w0 = s_Wn[k * 3 + 0], w1 = s_Wn[k * 3 + 1], w2v = s_Wn[k * 3 + 2];
#pragma unroll
                for (int nn = 0; nn < 4; ++nn) {
                    acc3[nn][0] = fmaf(a4[nn], w0, acc3[nn][0]);
                    acc3[nn][1] = fmaf(a4[nn], w1, acc3[nn][1]);
                    acc3[nn][2] = fmaf(a4[nn], w2v, acc3[nn][2]);
                }
            }
            if (c0 == 0) {
#pragma unroll
                for (int nn = 0; nn < 4; ++nn) {
                    int node = nbase + n0 + nn;
                    float dv = dinv[node];
                    hs3[node] = make_float4(dv * acc3[nn][0], dv * acc3[nn][1],
                                            dv * acc3[nn][2], 0.f);
                }
            }
        }
    }
}

// stage-2 aggregation: thread-per-node over CSR (cursor), plain stores, no atomics.
__global__ void __launch_bounds__(256)
k_agg3(const float4* __restrict__ hs3, const int* __restrict__ cursor,
       const int* __restrict__ ed, float4* __restrict__ y3agg) {
    int v = blockIdx.x * blockDim.x + threadIdx.x;
    if (v >= N_NODES) return;
    int end = cursor[v];
    int start = (v == 0) ? 0 : cursor[v - 1];
    float a0 = 0.f, a1 = 0.f, a2 = 0.f;
    int e = start;
    for (; e + 4 <= end; e += 4) {
        int s[4];
#pragma unroll
        for (int u = 0; u < 4; ++u) s[u] = ed[e + u];
#pragma unroll
        for (int u = 0; u < 4; ++u) {
            float4 h = hs3[s[u]];
            a0 += h.x; a1 += h.y; a2 += h.z;
        }
    }
    for (; e < end; ++e) {
        float4 h = hs3[ed[e]];
        a0 += h.x; a1 += h.y; a2 += h.z;
    }
    y3agg[v] = make_float4(a0, a1, a2, 0.f);
}

// stage-2 BN stats over y_final = dinv*(y3agg + 2*hs3) + b2
__global__ void __launch_bounds__(256)
k_bnstats3(const float4* __restrict__ y3agg, const float4* __restrict__ hs3,
           const float* __restrict__ dinv, const float* __restrict__ b2,
           float* __restrict__ bnsum) {
    int v = blockIdx.x * blockDim.x + threadIdx.x;
    float y0 = 0.f, y1 = 0.f, y2 = 0.f;
    if (v < N_NODES) {
        float dv = dinv[v];
        float4 ya = y3agg[v];
        float4 h = hs3[v];
        y0 = dv * (ya.x + 2.f * h.x) + b2[0];
        y1 = dv * (ya.y + 2.f * h.y) + b2[1];
        y2 = dv * (ya.z + 2.f * h.z) + b2[2];
    }
    __shared__ float sm[256];
    float vals[6] = {y0, y1, y2, y0 * y0, y1 * y1, y2 * y2};
    for (int c = 0; c < 6; ++c) {
        sm[threadIdx.x] = (v < N_NODES) ? vals[c] : 0.f;
        __syncthreads();
        for (int off = 128; off > 0; off >>= 1) {
            if (threadIdx.x < off) sm[threadIdx.x] += sm[threadIdx.x + off];
            __syncthreads();
        }
        if (threadIdx.x == 0) atomicAdd(&bnsum[c], sm[0]);
        __syncthreads();
    }
}

// final stage post: BN + pool(3,1) + leaky + 3x3 linear + leaky
__global__ void k_post3(const float4* __restrict__ y3agg, const float4* __restrict__ hs3,
                        const float* __restrict__ dinv, const float* __restrict__ b2,
                        const float* __restrict__ bnsum,
                        const float* __restrict__ g, const float* __restrict__ bb,
                        const float* __restrict__ lw, const float* __restrict__ lb,
                        float* __restrict__ out) {
    int v = blockIdx.x * blockDim.x + threadIdx.x;
    if (v >= N_NODES) return;
    float inv_n = 1.0f / (float)N_NODES;
    float sc[3], sh[3];
#pragma unroll
    for (int c = 0; c < 3; ++c) {
        float mean = bnsum[c] * inv_n;
        float var = fmaxf(bnsum[3 + c] * inv_n - mean * mean, 0.f);
        sc[c] = g[c] * rsqrtf(var + 1e-5f);
        sh[c] = bb[c] - mean * sc[c];
    }
    float dv = dinv[v];
    float4 ya = y3agg[v];
    float4 h = hs3[v];
    float z0 = fmaf(dv * (ya.x + 2.f * h.x) + b2[0], sc[0], sh[0]);
    float z1 = fmaf(dv * (ya.y + 2.f * h.y) + b2[1], sc[1], sh[1]);
    float z2 = fmaf(dv * (ya.z + 2.f * h.z) + b2[2], sc[2], sh[2]);
    float p0 = fmaxf(z0, z1);
    float p1 = fmaxf(p0, z2);
    float p2 = fmaxf(z1, z2);
    float a0 = leaky(p0), a1 = leaky(p1), a2 = leaky(p2);
    float o0 = leaky(lb[0] + a0 * lw[0] + a1 * lw[1] + a2 * lw[2]);
    float o1 = leaky(lb[1] + a0 * lw[3] + a1 * lw[4] + a2 * lw[5]);
    float o2 = leaky(lb[2] + a0 * lw[6] + a1 * lw[7] + a2 * lw[8]);
    out[v * 3 + 0] = o0;
    out[v * 3 + 1] = o1;
    out[v * 3 + 2] = o2;
}

// ---------------- launcher ----------------

extern "C" void kernel_launch(void* const* d_in, const int* in_sizes, int n_in,
                              void* d_out, int out_size, void* d_ws, size_t ws_size,
                              hipStream_t stream) {
    const float* x  = (const float*)d_in[0];
    const int*   ei = (const int*)d_in[1];
    const float* w0 = (const float*)d_in[2];
    const float* b0 = (const float*)d_in[3];
    const float* g0 = (const float*)d_in[4];
    const float* bb0 = (const float*)d_in[5];
    const float* lw0 = (const float*)d_in[6];
    const float* lb0 = (const float*)d_in[7];
    const float* w1 = (const float*)d_in[8];
    const float* b1 = (const float*)d_in[9];
    const float* g1 = (const float*)d_in[10];
    const float* bb1 = (const float*)d_in[11];
    const float* lw1 = (const float*)d_in[12];
    const float* lb1 = (const float*)d_in[13];
    const float* w2 = (const float*)d_in[14];
    const float* b2 = (const float*)d_in[15];
    const float* g2 = (const float*)d_in[16];
    const float* bb2 = (const float*)d_in[17];
    const float* lw2 = (const float*)d_in[18];
    const float* lb2 = (const float*)d_in[19];
    float* out = (float*)d_out;

    // workspace layout (16B-aligned first)
    char* w = (char*)d_ws;
    float* yagg = (float*)w;       w += (size_t)N_NODES * 64 * 4;   // 20.48 MB
    int* ed = (int*)w;             w += (size_t)N_EDGES * 4;        // 5.12 MB
    bf16* hs = (bf16*)w;           w += (size_t)N_NODES * 64 * 2;   // 10.24 MB
    float4* hs3 = (float4*)w;      w += (size_t)N_NODES * 16;       // 1.28 MB
    float4* y3agg = (float4*)w;    w += (size_t)N_NODES * 16;       // 1.28 MB
    int* deg = (int*)w;            w += (size_t)N_NODES * 4;
    float* dinv = (float*)w;       w += (size_t)N_NODES * 4;
    int* cursor = (int*)w;         w += (size_t)N_NODES * 4;
    int* chunk_node = (int*)w;     w += (N_CHUNKS + 1) * 4;
    int* partial = (int*)w;        w += 512 * 4;
    float* bnsum = (float*)w;      w += 384 * 4;
    int* tails = (int*)w;          w += 16 * 4;
    // pairs overlays yagg (dead until first memset); 10.56 MB <= 20.48 MB
    int2* pairs = (int2*)yagg;

    const int NB = (N_NODES + 255) / 256;  // 313

    // --- graph/CSR setup ---
    k_zero<<<NB, 256, 0, stream>>>(deg, bnsum, tails);
    k_part<<<N_EDGES / EPB, 256, 0, stream>>>(ei, pairs, tails);
    k_deg_bkt<<<2048, 256, 0, stream>>>(pairs, tails, deg);
    k_scanA<<<NB, 256, 0, stream>>>(deg, partial, dinv);
    k_scanB<<<1, 512, 0, stream>>>(partial, NB);
    k_scanC<<<NB, 256, 0, stream>>>(deg, partial, cursor);
    k_scatter2<<<2048, 256, 0, stream>>>(pairs, tails, cursor, ed);
    k_chunknode<<<(N_CHUNKS + 256) / 256, 256, 0, stream>>>(cursor, chunk_node);

    // --- stage 0 ---
    k_h0s<<<(N_NODES * 64 + 255) / 256, 256, 0, stream>>>(x, w0, dinv, hs);
    hipMemsetAsync(yagg, 0, (size_t)N_NODES * 64 * 4, stream);  // pairs dead now
    k_agg_seg<<<2500, 256, 0, stream>>>(hs, ed, cursor, chunk_node, yagg);
    k_bnstats<<<640, 256, 0, stream>>>(yagg, hs, dinv, b0, bnsum);
    k_post64<1, 0><<<1250, 128, 0, stream>>>(yagg, hs, dinv, b0, bnsum, g0, bb0,
                                             lw0, lb0, w1, hs, nullptr);

    // --- stage 1 ---
    hipMemsetAsync(yagg, 0, (size_t)N_NODES * 64 * 4, stream);
    k_agg_seg<<<2500, 256, 0, stream>>>(hs, ed, cursor, chunk_node, yagg);
    k_bnstats<<<640, 256, 0, stream>>>(yagg, hs, dinv, b1, bnsum + 128);
    k_post64<2, 1><<<1250, 128, 0, stream>>>(yagg, hs, dinv, b1, bnsum + 128, g1, bb1,
                                             lw1, lb1, w2, nullptr, hs3);

    // --- stage 2 (C=3) ---
    k_agg3<<<NB, 256, 0, stream>>>(hs3, cursor, ed, y3agg);
    k_bnstats3<<<NB, 256, 0, stream>>>(y3agg, hs3, dinv, b2, bnsum + 256);
    k_post3<<<NB, 256, 0, stream>>>(y3agg, hs3, dinv, b2, bnsum + 256,
                                    g2, bb2, lw2, lb2, out);
}